// Round 3
// baseline (867.376 us; speedup 1.0000x reference)
//
#include <hip/hip_runtime.h>
#include <math.h>

#define DIM 1024
#define NEXP 64
#define TOPK 8
#define BM 128             // tokens per block
#define BK 64              // k-chunk staged in LDS
#define NCHUNK (DIM / BK)  // 16
#define THREADS 256
#define XPAD 68            // staged-tile row stride (16B aligned; <=2-way banks)
#define LPAD 65            // logits row stride

// Thread grid: 16 rows (trow) x 16 cols (tcol).
// Tokens:  t_i = trow + 16*i, i<8  (strided -> 2-way-max LDS banks)
// Experts: e_j = tcol + 16*j, j<4
__global__ __launch_bounds__(THREADS, 1)
void router_topk_kernel(const float* __restrict__ x,
                        const float* __restrict__ W,
                        const float* __restrict__ b,
                        float* __restrict__ out_probs,
                        float* __restrict__ out_idx)
{
    __shared__ float x_s[2][BM][XPAD];      // 69.6 KB
    __shared__ float w_s[2][NEXP][XPAD];    // 34.8 KB
    __shared__ float logits_s[BM][LPAD];    // 33.3 KB
    __shared__ float topk_s[BM][TOPK];      //  4.1 KB   (total ~142 KB, 1 block/CU)

    const int tid  = threadIdx.x;
    const int trow = tid >> 4;   // 0..15
    const int tcol = tid & 15;   // 0..15
    const int tok0 = blockIdx.x * BM;

    float bb[4];
#pragma unroll
    for (int j = 0; j < 4; ++j) bb[j] = b[tcol + 16 * j];

    float acc[8][4];
#pragma unroll
    for (int i = 0; i < 8; ++i)
#pragma unroll
        for (int j = 0; j < 4; ++j) acc[i][j] = 0.f;

    // staging: x tile 128x64 = 2048 f4 -> 8/thread ; w tile 64x64 = 1024 f4 -> 4/thread
    auto prefetch = [&](float4 (&px)[8], float4 (&pw)[4], int kc) {
        const float* xsrc = x + (size_t)tok0 * DIM + (size_t)kc * BK;
        const float* wsrc = W + (size_t)kc * BK;
#pragma unroll
        for (int i = 0; i < 8; ++i) {
            int v = tid + i * THREADS;
            int row = v >> 4, c4 = v & 15;
            px[i] = *(const float4*)(xsrc + (size_t)row * DIM + c4 * 4);
        }
#pragma unroll
        for (int i = 0; i < 4; ++i) {
            int v = tid + i * THREADS;
            int row = v >> 4, c4 = v & 15;
            pw[i] = *(const float4*)(wsrc + (size_t)row * DIM + c4 * 4);
        }
    };
    auto stage_write = [&](float4 (&px)[8], float4 (&pw)[4], int buf) {
#pragma unroll
        for (int i = 0; i < 8; ++i) {
            int v = tid + i * THREADS;
            int row = v >> 4, c4 = v & 15;
            *(float4*)&x_s[buf][row][c4 * 4] = px[i];
        }
#pragma unroll
        for (int i = 0; i < 4; ++i) {
            int v = tid + i * THREADS;
            int row = v >> 4, c4 = v & 15;
            *(float4*)&w_s[buf][row][c4 * 4] = pw[i];
        }
    };
    auto compute = [&](int buf) {
#pragma unroll
        for (int k4 = 0; k4 < BK / 4; ++k4) {
            float4 xa[8], wa[4];
#pragma unroll
            for (int i = 0; i < 8; ++i)
                xa[i] = *(const float4*)&x_s[buf][trow + 16 * i][k4 * 4];
#pragma unroll
            for (int j = 0; j < 4; ++j)
                wa[j] = *(const float4*)&w_s[buf][tcol + 16 * j][k4 * 4];
#pragma unroll
            for (int i = 0; i < 8; ++i)
#pragma unroll
                for (int j = 0; j < 4; ++j) {
                    acc[i][j] = fmaf(xa[i].x, wa[j].x, acc[i][j]);
                    acc[i][j] = fmaf(xa[i].y, wa[j].y, acc[i][j]);
                    acc[i][j] = fmaf(xa[i].z, wa[j].z, acc[i][j]);
                    acc[i][j] = fmaf(xa[i].w, wa[j].w, acc[i][j]);
                }
        }
    };

    // ---- 2-phase pipeline: one barrier per chunk, dbuf LDS ----
    float4 px[8], pw[4];
    prefetch(px, pw, 0);
    stage_write(px, pw, 0);
    __syncthreads();
    for (int kc = 0; kc < NCHUNK; ++kc) {
        const int cur = kc & 1;
        if (kc + 1 < NCHUNK) prefetch(px, pw, kc + 1);   // issue early
        compute(cur);                                    // hides global latency
        if (kc + 1 < NCHUNK) stage_write(px, pw, cur ^ 1); // write late (vmcnt lands here)
        __syncthreads();
    }

    // ---- logits (+bias) to LDS ----
#pragma unroll
    for (int i = 0; i < 8; ++i)
#pragma unroll
        for (int j = 0; j < 4; ++j)
            logits_s[trow + 16 * i][tcol + 16 * j] = acc[i][j] + bb[j];
    __syncthreads();

    // ---- top-8 + softmax: one lane per token (2 waves) ----
    if (tid < BM) {
        const int t = tid;
        float pv[TOPK]; int pi[TOPK];
#pragma unroll
        for (int k = 0; k < TOPK; ++k) {
            float vmax = -INFINITY; int imax = 0;
#pragma unroll
            for (int e = 0; e < NEXP; ++e) {
                float v = logits_s[t][e];
                if (v > vmax) { vmax = v; imax = e; }   // strict > == lowest-index tie-break
            }
            pv[k] = vmax; pi[k] = imax;
            logits_s[t][imax] = -INFINITY;
        }
        float p[TOPK]; float s = 0.f;
#pragma unroll
        for (int k = 0; k < TOPK; ++k) { p[k] = __expf(pv[k] - pv[0]); s += p[k]; }
        float inv = 1.f / s;

#pragma unroll
        for (int e = 0; e < NEXP; ++e) logits_s[t][e] = 0.f;
#pragma unroll
        for (int k = 0; k < TOPK; ++k) {
            logits_s[t][pi[k]] = p[k] * inv;
            topk_s[t][k] = (float)pi[k];
        }
    }
    __syncthreads();

    // ---- coalesced outputs: probs 128x64 = 2048 f4 (8/thread) ----
#pragma unroll
    for (int i = 0; i < 8; ++i) {
        int v = tid + i * THREADS;
        int row = v >> 4, c = (v & 15) * 4;
        float4 z = make_float4(logits_s[row][c], logits_s[row][c + 1],
                               logits_s[row][c + 2], logits_s[row][c + 3]);
        *(float4*)(out_probs + (size_t)(tok0 + row) * NEXP + c) = z;
    }
    // indices: 128x8 floats = 256 f4, one per thread
    {
        int row = tid >> 1, c4 = tid & 1;
        float4 z = *(const float4*)&topk_s[row][c4 * 4];
        *(float4*)(out_idx + (size_t)(tok0 + row) * TOPK + c4 * 4) = z;
    }
}

extern "C" void kernel_launch(void* const* d_in, const int* in_sizes, int n_in,
                              void* d_out, int out_size, void* d_ws, size_t ws_size,
                              hipStream_t stream) {
    const float* x = (const float*)d_in[0];
    const float* W = (const float*)d_in[1];
    const float* b = (const float*)d_in[2];
    float* out = (float*)d_out;

    const int ntok = in_sizes[0] / DIM;           // 32768
    float* out_probs = out;                        // [ntok, 64]
    float* out_idx   = out + (size_t)ntok * NEXP;  // [ntok, 8] as float values

    const int grid = ntok / BM;                    // 256 blocks (1/CU)
    router_topk_kernel<<<grid, THREADS, 0, stream>>>(x, W, b, out_probs, out_idx);
}

// Round 4
// 255.484 us; speedup vs baseline: 3.3950x; 3.3950x over previous
//
#include <hip/hip_runtime.h>
#include <math.h>

#define DIM 1024
#define NEXP 64
#define TOPK 8
#define BM 128             // tokens per block
#define BK 64              // k-chunk (16 x 16B chunks per row)
#define NCHUNK (DIM / BK)  // 16
#define THREADS 256
#define LPAD 65

// global -> LDS direct DMA, 16B per lane
__device__ __forceinline__ void gload16(const float* g, float* l) {
    __builtin_amdgcn_global_load_lds(
        (const __attribute__((address_space(1))) void*)g,
        (__attribute__((address_space(3))) void*)l, 16, 0, 0);
}

__global__ __launch_bounds__(THREADS, 1)
void router_topk_kernel(const float* __restrict__ x,
                        const float* __restrict__ W,
                        const float* __restrict__ b,
                        float* __restrict__ out_probs,
                        float* __restrict__ out_idx)
{
    // linear rows (stride 64 floats) — REQUIRED by global_load_lds.
    // LDS[r][c] holds logical 16B-chunk (c ^ (r&15)) of row r (source-swizzled).
    __shared__ float x_s[2][BM][BK];     // 64 KB
    __shared__ float w_s[2][NEXP][BK];   // 32 KB
    __shared__ float logits_s[BM][LPAD]; // 33.3 KB
    __shared__ float topk_s[BM][TOPK];   //  4 KB

    const int tid  = threadIdx.x;
    const int trow = tid >> 4;    // 0..15 token group
    const int tcol = tid & 15;    // 0..15 expert group
    const int lane = tid & 63;
    const int wv   = tid >> 6;    // wave 0..3
    const int tok0 = blockIdx.x * BM;

    float bb[4];
#pragma unroll
    for (int j = 0; j < 4; ++j) bb[j] = b[tcol + 16 * j];

    float acc[8][4];
#pragma unroll
    for (int i = 0; i < 8; ++i)
#pragma unroll
        for (int j = 0; j < 4; ++j) acc[i][j] = 0.f;

    // ---- async staging: per issue, 64 lanes x 16B = 4 rows. Wave wv owns
    // x rows [wv*32, wv*32+32) (8 issues) and W rows [wv*16, wv*16+16) (4 issues).
    const int rl = lane >> 4;          // 0..3 row within issue
    const int c  = lane & 15;          // phys 16B chunk
    auto stage = [&](int buf, int kc) {
#pragma unroll
        for (int k = 0; k < 8; ++k) {
            int r  = wv * 32 + k * 4 + rl;
            int cs = c ^ (r & 15);                       // inverse-swizzled source
            gload16(x + (size_t)(tok0 + r) * DIM + kc * BK + cs * 4,
                    &x_s[buf][r][c * 4]);
        }
#pragma unroll
        for (int k = 0; k < 4; ++k) {
            int r  = wv * 16 + k * 4 + rl;
            int cs = c ^ (r & 15);
            gload16(W + (size_t)r * DIM + kc * BK + cs * 4,
                    &w_s[buf][r][c * 4]);
        }
    };

    auto compute = [&](int buf) {
#pragma unroll
        for (int k4 = 0; k4 < 16; ++k4) {
            // phys chunk k4^trow at row trow+16i -> logical chunk k4 (XOR cancels)
            const int cx = (k4 ^ trow) * 4;
            const int cw = (k4 ^ tcol) * 4;
            float4 xa[8], wa[4];
#pragma unroll
            for (int i = 0; i < 8; ++i)
                xa[i] = *(const float4*)&x_s[buf][trow + 16 * i][cx];
#pragma unroll
            for (int j = 0; j < 4; ++j)
                wa[j] = *(const float4*)&w_s[buf][tcol + 16 * j][cw];
#pragma unroll
            for (int i = 0; i < 8; ++i)
#pragma unroll
                for (int j = 0; j < 4; ++j) {
                    acc[i][j] = fmaf(xa[i].x, wa[j].x, acc[i][j]);
                    acc[i][j] = fmaf(xa[i].y, wa[j].y, acc[i][j]);
                    acc[i][j] = fmaf(xa[i].z, wa[j].z, acc[i][j]);
                    acc[i][j] = fmaf(xa[i].w, wa[j].w, acc[i][j]);
                }
        }
    };

    // ---- 2-phase pipeline: one barrier per chunk; DMA in flight under compute
    stage(0, 0);
    __syncthreads();                       // drains vmcnt: chunk 0 resident
    for (int kc = 0; kc < NCHUNK; ++kc) {
        const int cur = kc & 1;
        if (kc + 1 < NCHUNK) stage(cur ^ 1, kc + 1);   // issue-early
        compute(cur);                                  // hides HBM latency
        __syncthreads();                               // vmcnt(0)+lgkm drain
    }

    // ---- logits (+bias) to LDS ----
#pragma unroll
    for (int i = 0; i < 8; ++i)
#pragma unroll
        for (int j = 0; j < 4; ++j)
            logits_s[trow + 16 * i][tcol + 16 * j] = acc[i][j] + bb[j];
    __syncthreads();

    // ---- top-8 + softmax: one lane per token ----
    if (tid < BM) {
        const int t = tid;
        float pv[TOPK]; int pi[TOPK];
#pragma unroll
        for (int k = 0; k < TOPK; ++k) {
            float vmax = -INFINITY; int imax = 0;
#pragma unroll
            for (int e = 0; e < NEXP; ++e) {
                float v = logits_s[t][e];
                if (v > vmax) { vmax = v; imax = e; }   // strict > == lowest-index tie-break
            }
            pv[k] = vmax; pi[k] = imax;
            logits_s[t][imax] = -INFINITY;
        }
        float p[TOPK]; float s = 0.f;
#pragma unroll
        for (int k = 0; k < TOPK; ++k) { p[k] = __expf(pv[k] - pv[0]); s += p[k]; }
        float inv = 1.f / s;

#pragma unroll
        for (int e = 0; e < NEXP; ++e) logits_s[t][e] = 0.f;
#pragma unroll
        for (int k = 0; k < TOPK; ++k) {
            logits_s[t][pi[k]] = p[k] * inv;
            topk_s[t][k] = (float)pi[k];
        }
    }
    __syncthreads();

    // ---- coalesced outputs: probs 128x64 = 2048 f4, 8 per thread ----
#pragma unroll
    for (int i = 0; i < 8; ++i) {
        int v = tid + i * THREADS;
        int row = v >> 4, cc = (v & 15) * 4;
        float4 z = make_float4(logits_s[row][cc], logits_s[row][cc + 1],
                               logits_s[row][cc + 2], logits_s[row][cc + 3]);
        *(float4*)(out_probs + (size_t)(tok0 + row) * NEXP + cc) = z;
    }
    // indices: 128x8 floats = 256 f4, one per thread
    {
        int row = tid >> 1, c4 = tid & 1;
        float4 z = *(const float4*)&topk_s[row][c4 * 4];
        *(float4*)(out_idx + (size_t)(tok0 + row) * TOPK + c4 * 4) = z;
    }
}

extern "C" void kernel_launch(void* const* d_in, const int* in_sizes, int n_in,
                              void* d_out, int out_size, void* d_ws, size_t ws_size,
                              hipStream_t stream) {
    const float* x = (const float*)d_in[0];
    const float* W = (const float*)d_in[1];
    const float* b = (const float*)d_in[2];
    float* out = (float*)d_out;

    const int ntok = in_sizes[0] / DIM;           // 32768
    float* out_probs = out;                        // [ntok, 64]
    float* out_idx   = out + (size_t)ntok * NEXP;  // [ntok, 8] as float values

    const int grid = ntok / BM;                    // 256 blocks = 1 per CU
    router_topk_kernel<<<grid, THREADS, 0, stream>>>(x, W, b, out_probs, out_idx);
}

// Round 5
// 235.171 us; speedup vs baseline: 3.6883x; 1.0864x over previous
//
#include <hip/hip_runtime.h>
#include <math.h>

#define DIM 1024
#define NEXP 64
#define TOPK 8
#define BM 128             // tokens per block
#define KSPLIT 2
#define KHALF (DIM / KSPLIT)   // 512
#define BK 32              // k-chunk (8 x 16B chunks per row)
#define NCHUNK (KHALF / BK)    // 16
#define THREADS 256
#define LPAD 65

// global -> LDS direct DMA, 16B per lane
__device__ __forceinline__ void gload16(const float* g, float* l) {
    __builtin_amdgcn_global_load_lds(
        (const __attribute__((address_space(1))) void*)g,
        (__attribute__((address_space(3))) void*)l, 16, 0, 0);
}

// ---------------- kernel 1: partial GEMM (one K-half per block) ----------------
__global__ __launch_bounds__(THREADS, 2)
void router_gemm_partial(const float* __restrict__ x,
                         const float* __restrict__ W,
                         float* __restrict__ part)   // [tiles][2][BM][NEXP]
{
    // linear rows (stride 32 floats = 128 B); LDS[r][c] holds logical chunk c^(r&7)
    __shared__ float x_s[2][BM][BK];     // 32 KB
    __shared__ float w_s[2][NEXP][BK];   // 16 KB   (total 48 KB -> 2 blocks/CU at grid 512)

    const int tid  = threadIdx.x;
    const int trow = tid >> 4;    // 0..15
    const int tcol = tid & 15;    // 0..15
    const int tile = blockIdx.x;
    const int half = blockIdx.y;
    const int tok0 = tile * BM;
    const int k0   = half * KHALF;

    float acc[8][4];
#pragma unroll
    for (int i = 0; i < 8; ++i)
#pragma unroll
        for (int j = 0; j < 4; ++j) acc[i][j] = 0.f;

    const int rr = tid >> 3;     // 0..31 row-in-32-group
    const int c  = tid & 7;      // phys 16B chunk
    auto stage = [&](int buf, int kc) {
#pragma unroll
        for (int m = 0; m < 4; ++m) {                  // x: 4 x 32 rows
            int r  = m * 32 + rr;
            int cs = c ^ (r & 7);
            gload16(x + (size_t)(tok0 + r) * DIM + k0 + kc * BK + cs * 4,
                    &x_s[buf][r][c * 4]);
        }
#pragma unroll
        for (int m = 0; m < 2; ++m) {                  // W: 2 x 32 rows
            int r  = m * 32 + rr;
            int cs = c ^ (r & 7);
            gload16(W + (size_t)r * DIM + k0 + kc * BK + cs * 4,
                    &w_s[buf][r][c * 4]);
        }
    };

    auto compute = [&](int buf) {
#pragma unroll
        for (int k4 = 0; k4 < 8; ++k4) {
            const int cx = (k4 ^ (trow & 7)) * 4;
            const int cw = (k4 ^ (tcol & 7)) * 4;
            float4 xa[8], wa[4];
#pragma unroll
            for (int i = 0; i < 8; ++i)
                xa[i] = *(const float4*)&x_s[buf][trow + 16 * i][cx];
#pragma unroll
            for (int j = 0; j < 4; ++j)
                wa[j] = *(const float4*)&w_s[buf][tcol + 16 * j][cw];
#pragma unroll
            for (int i = 0; i < 8; ++i)
#pragma unroll
                for (int j = 0; j < 4; ++j) {
                    acc[i][j] = fmaf(xa[i].x, wa[j].x, acc[i][j]);
                    acc[i][j] = fmaf(xa[i].y, wa[j].y, acc[i][j]);
                    acc[i][j] = fmaf(xa[i].z, wa[j].z, acc[i][j]);
                    acc[i][j] = fmaf(xa[i].w, wa[j].w, acc[i][j]);
                }
        }
    };

    stage(0, 0);
    __syncthreads();
    for (int kc = 0; kc < NCHUNK; ++kc) {
        const int cur = kc & 1;
        if (kc + 1 < NCHUNK) stage(cur ^ 1, kc + 1);   // issue-early DMA
        compute(cur);                                  // hides latency
        __syncthreads();
    }

    // ---- stage partials through LDS (overlay on x_s, free after last barrier) ----
    float* sstage = &x_s[0][0][0];                     // 8192 floats = [BM][64]
#pragma unroll
    for (int i = 0; i < 8; ++i)
#pragma unroll
        for (int j = 0; j < 4; ++j)
            sstage[(trow + 16 * i) * NEXP + tcol + 16 * j] = acc[i][j];
    __syncthreads();

    float* dst = part + ((size_t)(tile * KSPLIT + half) * BM) * NEXP;
#pragma unroll
    for (int it = 0; it < 8; ++it) {
        int v = tid + it * THREADS;                    // 2048 f4
        *(float4*)(dst + v * 4) = *(const float4*)(sstage + v * 4);
    }
}

// ---------------- kernel 2: reduce halves + bias + top-8 + softmax ----------------
__global__ __launch_bounds__(THREADS, 1)
void router_topk_finalize(const float* __restrict__ part,
                          const float* __restrict__ b,
                          float* __restrict__ out_probs,
                          float* __restrict__ out_idx)
{
    __shared__ float logits_s[BM][LPAD];
    __shared__ float topk_s[BM][TOPK];

    const int tid  = threadIdx.x;
    const int tile = blockIdx.x;
    const int tok0 = tile * BM;

    const float* p0 = part + ((size_t)(tile * KSPLIT + 0) * BM) * NEXP;
    const float* p1 = part + ((size_t)(tile * KSPLIT + 1) * BM) * NEXP;

    // load + reduce + bias, coalesced f4
#pragma unroll
    for (int it = 0; it < 8; ++it) {
        int v = tid + it * THREADS;
        int r = v >> 4, c4 = (v & 15) * 4;
        float4 a = *(const float4*)(p0 + (size_t)r * NEXP + c4);
        float4 d = *(const float4*)(p1 + (size_t)r * NEXP + c4);
        float4 bv = *(const float4*)(b + c4);
        logits_s[r][c4 + 0] = a.x + d.x + bv.x;
        logits_s[r][c4 + 1] = a.y + d.y + bv.y;
        logits_s[r][c4 + 2] = a.z + d.z + bv.z;
        logits_s[r][c4 + 3] = a.w + d.w + bv.w;
    }
    __syncthreads();

    if (tid < BM) {
        const int t = tid;
        float pv[TOPK]; int pi[TOPK];
#pragma unroll
        for (int k = 0; k < TOPK; ++k) {
            float vmax = -INFINITY; int imax = 0;
#pragma unroll
            for (int e = 0; e < NEXP; ++e) {
                float v = logits_s[t][e];
                if (v > vmax) { vmax = v; imax = e; }   // strict > == lowest-index tie-break
            }
            pv[k] = vmax; pi[k] = imax;
            logits_s[t][imax] = -INFINITY;
        }
        float p[TOPK]; float s = 0.f;
#pragma unroll
        for (int k = 0; k < TOPK; ++k) { p[k] = __expf(pv[k] - pv[0]); s += p[k]; }
        float inv = 1.f / s;

#pragma unroll
        for (int e = 0; e < NEXP; ++e) logits_s[t][e] = 0.f;
#pragma unroll
        for (int k = 0; k < TOPK; ++k) {
            logits_s[t][pi[k]] = p[k] * inv;
            topk_s[t][k] = (float)pi[k];
        }
    }
    __syncthreads();

#pragma unroll
    for (int it = 0; it < 8; ++it) {
        int v = tid + it * THREADS;
        int r = v >> 4, c4 = (v & 15) * 4;
        float4 z = make_float4(logits_s[r][c4], logits_s[r][c4 + 1],
                               logits_s[r][c4 + 2], logits_s[r][c4 + 3]);
        *(float4*)(out_probs + (size_t)(tok0 + r) * NEXP + c4) = z;
    }
    {
        int r = tid >> 1, c4 = tid & 1;
        float4 z = *(const float4*)&topk_s[r][c4 * 4];
        *(float4*)(out_idx + (size_t)(tok0 + r) * TOPK + c4 * 4) = z;
    }
}

extern "C" void kernel_launch(void* const* d_in, const int* in_sizes, int n_in,
                              void* d_out, int out_size, void* d_ws, size_t ws_size,
                              hipStream_t stream) {
    const float* x = (const float*)d_in[0];
    const float* W = (const float*)d_in[1];
    const float* b = (const float*)d_in[2];
    float* out = (float*)d_out;

    const int ntok = in_sizes[0] / DIM;            // 32768
    float* out_probs = out;                         // [ntok, 64]
    float* out_idx   = out + (size_t)ntok * NEXP;   // [ntok, 8] as float values
    float* part      = (float*)d_ws;                // [ntok/BM][2][BM][64] = 16 MB

    const int tiles = ntok / BM;                    // 256
    router_gemm_partial<<<dim3(tiles, KSPLIT), THREADS, 0, stream>>>(x, W, part);
    router_topk_finalize<<<tiles, THREADS, 0, stream>>>(part, b, out_probs, out_idx);
}